// Round 3
// baseline (99.799 us; speedup 1.0000x reference)
//
#include <hip/hip_runtime.h>
#include <math.h>

#define N_QUBITS 4
#define N_LAYERS 6
#define NW (N_LAYERS * N_QUBITS)
#define M 4   // samples per thread in qeval

// ---------------------------------------------------------------------------
// Prep kernel (1 block): build W (16x16 complex) from the 24 RX gates + CNOT
// rings, form S_q = Re(W^dag Z_q W), contract to 4x81 multilinear table C:
//   out_q(x) = sum_{t in {I,Z,X}^4} C_q[t] * prod_p (1, cos x_p, sin x_p)[t_p]
// All loops fully unrolled so re[]/im[] stay in registers (no scratch).
// ---------------------------------------------------------------------------
__global__ __launch_bounds__(256) void qprep_kernel(
    const float* __restrict__ weights, float* __restrict__ Ctab)
{
    __shared__ float Wr[16][16];
    __shared__ float Wi[16][16];
    __shared__ float S[4][16][16];
    __shared__ float wc[NW], ws[NW];
    const int tid = threadIdx.x;
    if (tid < NW) {
        float t = weights[tid] * 0.5f;
        wc[tid] = cosf(t);
        ws[tid] = sinf(t);
    }
    __syncthreads();

    // Phase 1: threads 0..15 build column `tid` of W
    if (tid < 16) {
        float re[16], im[16];
#pragma unroll
        for (int k = 0; k < 16; ++k) { re[k] = 0.f; im[k] = 0.f; }
        re[tid] = 1.f;  // LDS? no - tid is register; dynamic index into re[]...
        // avoid dynamic index: rebuild via compare
#pragma unroll
        for (int k = 0; k < 16; ++k) re[k] = (k == tid) ? 1.f : 0.f;
#pragma unroll
        for (int l = 0; l < N_LAYERS; ++l) {
#pragma unroll
            for (int q = 0; q < 4; ++q) {
                const float ct = wc[l * 4 + q], sn = ws[l * 4 + q];
                const int mask = 8 >> q;
#pragma unroll
                for (int idx = 0; idx < 16; ++idx) {
                    if (idx & mask) continue;
                    const int j = idx | mask;
                    float r0 = re[idx], u0 = im[idx], r1 = re[j], u1 = im[j];
                    re[idx] = ct * r0 + sn * u1; im[idx] = ct * u0 - sn * r1;
                    re[j]   = ct * r1 + sn * u0; im[j]   = ct * u1 - sn * r0;
                }
            }
#pragma unroll
            for (int q = 0; q < 4; ++q) {
                const int cm = 8 >> q, tm = 8 >> ((q + 1) & 3);
#pragma unroll
                for (int idx = 0; idx < 16; ++idx) {
                    if ((idx & cm) && !(idx & tm)) {
                        const int j = idx | tm;
                        float t0 = re[idx]; re[idx] = re[j]; re[j] = t0;
                        float t1 = im[idx]; im[idx] = im[j]; im[j] = t1;
                    }
                }
            }
        }
#pragma unroll
        for (int k = 0; k < 16; ++k) { Wr[k][tid] = re[k]; Wi[k][tid] = im[k]; }
    }
    __syncthreads();

    // Phase 2: thread (i,j): S_q[i][j] = sum_k z_q(k) Re(W[k,i] conj(W[k,j]))
    {
        const int i = tid >> 4, j = tid & 15;
        float acc0 = 0.f, acc1 = 0.f, acc2 = 0.f, acc3 = 0.f;
#pragma unroll
        for (int k = 0; k < 16; ++k) {
            const float prod = Wr[k][i] * Wr[k][j] + Wi[k][i] * Wi[k][j];
            acc0 += (k & 8) ? -prod : prod;
            acc1 += (k & 4) ? -prod : prod;
            acc2 += (k & 2) ? -prod : prod;
            acc3 += (k & 1) ? -prod : prod;
        }
        S[0][i][j] = acc0; S[1][i][j] = acc1; S[2][i][j] = acc2; S[3][i][j] = acc3;
    }
    __syncthreads();

    // Phase 3: C_q[t] = (1/16) sum_i (-1)^popc(i&zm) S_q[i][i^xm]
    if (tid < 81) {
        const int t1 = tid / 27, t2 = (tid / 9) % 3, t3 = (tid / 3) % 3, t4 = tid % 3;
        int zm = 0, xm = 0;
        if (t1 == 1) zm |= 8; else if (t1 == 2) xm |= 8;
        if (t2 == 1) zm |= 4; else if (t2 == 2) xm |= 4;
        if (t3 == 1) zm |= 2; else if (t3 == 2) xm |= 2;
        if (t4 == 1) zm |= 1; else if (t4 == 2) xm |= 1;
#pragma unroll
        for (int q = 0; q < 4; ++q) {
            float acc = 0.f;
#pragma unroll
            for (int i = 0; i < 16; ++i) {
                const float v = S[q][i][i ^ xm];
                acc += (__popc(i & zm) & 1) ? -v : v;
            }
            Ctab[q * 81 + tid] = acc * 0.0625f;
        }
    }
}

// ---------------------------------------------------------------------------
// Main kernel: M samples/thread, sample loop innermost so each wave-uniform
// coefficient load (literal offset -> expected s_load) feeds M*2 FMAs.
// 80 FMA per output (Horner-optimal for 81 coeffs).
// ---------------------------------------------------------------------------
__global__ __launch_bounds__(256) void qeval_kernel(
    const float* __restrict__ x, const float* __restrict__ Ctab,
    float* __restrict__ out, int B)
{
    const int tid = threadIdx.x;
    const int base = blockIdx.x * (256 * M) + tid;

    float4 xv[M];
#pragma unroll
    for (int m = 0; m < M; ++m) {
        const int b = base + m * 256;
        xv[m] = (b < B) ? reinterpret_cast<const float4*>(x)[b]
                        : make_float4(0.f, 0.f, 0.f, 0.f);
    }

    // per-sample trig: vc[m][p], vs[m][p] for qubit p
    float vc[M][4], vs[M][4];
#pragma unroll
    for (int m = 0; m < M; ++m) {
        vc[m][0] = __cosf(xv[m].x); vs[m][0] = __sinf(xv[m].x);
        vc[m][1] = __cosf(xv[m].y); vs[m][1] = __sinf(xv[m].y);
        vc[m][2] = __cosf(xv[m].z); vs[m][2] = __sinf(xv[m].z);
        vc[m][3] = __cosf(xv[m].w); vs[m][3] = __sinf(xv[m].w);
    }

    float o[M][4];
#pragma unroll
    for (int q = 0; q < 4; ++q) {
        const float* __restrict__ Cq = Ctab + q * 81;
        float s1[M];
#pragma unroll
        for (int m = 0; m < M; ++m) s1[m] = 0.f;
#pragma unroll
        for (int t1 = 0; t1 < 3; ++t1) {
            float s2[M];
#pragma unroll
            for (int m = 0; m < M; ++m) s2[m] = 0.f;
#pragma unroll
            for (int t2 = 0; t2 < 3; ++t2) {
                float s3[M];
#pragma unroll
                for (int m = 0; m < M; ++m) s3[m] = 0.f;
#pragma unroll
                for (int t3 = 0; t3 < 3; ++t3) {
                    const int b3 = ((t1 * 3 + t2) * 3 + t3) * 3;
                    const float c0 = Cq[b3];
                    const float c1 = Cq[b3 + 1];
                    const float c2 = Cq[b3 + 2];
#pragma unroll
                    for (int m = 0; m < M; ++m) {
                        float e = c0;
                        e = fmaf(c1, vc[m][3], e);
                        e = fmaf(c2, vs[m][3], e);
                        if (t3 == 0)      s3[m] += e;
                        else if (t3 == 1) s3[m] = fmaf(e, vc[m][2], s3[m]);
                        else              s3[m] = fmaf(e, vs[m][2], s3[m]);
                    }
                }
#pragma unroll
                for (int m = 0; m < M; ++m) {
                    if (t2 == 0)      s2[m] += s3[m];
                    else if (t2 == 1) s2[m] = fmaf(s3[m], vc[m][1], s2[m]);
                    else              s2[m] = fmaf(s3[m], vs[m][1], s2[m]);
                }
            }
#pragma unroll
            for (int m = 0; m < M; ++m) {
                if (t1 == 0)      s1[m] += s2[m];
                else if (t1 == 1) s1[m] = fmaf(s2[m], vc[m][0], s1[m]);
                else              s1[m] = fmaf(s2[m], vs[m][0], s1[m]);
            }
        }
#pragma unroll
        for (int m = 0; m < M; ++m) o[m][q] = s1[m];
    }

#pragma unroll
    for (int m = 0; m < M; ++m) {
        const int b = base + m * 256;
        if (b < B)
            reinterpret_cast<float4*>(out)[b] =
                make_float4(o[m][0], o[m][1], o[m][2], o[m][3]);
    }
}

extern "C" void kernel_launch(void* const* d_in, const int* in_sizes, int n_in,
                              void* d_out, int out_size, void* d_ws, size_t ws_size,
                              hipStream_t stream) {
    const float* x = (const float*)d_in[0];
    const float* weights = (const float*)d_in[1];
    float* out = (float*)d_out;
    float* Ctab = (float*)d_ws;   // 324 floats
    const int B = in_sizes[0] / 4;

    qprep_kernel<<<1, 256, 0, stream>>>(weights, Ctab);

    const int spb = 256 * M;
    const int grid = (B + spb - 1) / spb;
    qeval_kernel<<<grid, 256, 0, stream>>>(x, Ctab, out, B);
}